// Round 8
// baseline (172.333 us; speedup 1.0000x reference)
//
#include <hip/hip_runtime.h>
#include <stdint.h>

// KAN layer as bf16 MFMA GEMM: out = phi @ W^T + bias
//   phi[b, i*8+g] = normalized cubic-bump basis (g<5; 3 zero-pad cols)
// M=32768, N=256, K=2048 (64 kt-iters of BK=32).
// R8: SPLIT-K x2 -> grid 1024 blocks = 4 blocks/CU = 4 waves/SIMD (was 2).
//     R4-R7 invariant: 2 waves/SIMD, pipes MFMA/VALU/LDS each ~40% busy,
//     sum ~100% -> occupancy-starved overlap. Split-K adds no basis VALU
//     (disjoint i-ranges), LDS chunk shrunk to 2x16 KB (33 KB -> 4 blk/CU),
//     launch_bounds(256,4). k-halves combine via fp32 atomicAdd (L2 RMW)
//     onto memset-zeroed out; kb=0 adds bias.

#define B_SZ   32768
#define IN_SZ  256
#define OUT_SZ 256
#define EPSF   1e-8f

typedef __bf16 bf16x8 __attribute__((ext_vector_type(8)));
typedef unsigned short ushort8 __attribute__((ext_vector_type(8)));
typedef float floatx16 __attribute__((ext_vector_type(16)));

union frag_u { uint4 u; bf16x8 v; };

__device__ __forceinline__ unsigned short f2bf(float f) {
  unsigned u = __float_as_uint(f);
  u += 0x7FFFu + ((u >> 16) & 1u);
  return (unsigned short)(u >> 16);
}

// Wf fragment-order chunk index for (o, i): 16B chunk = 8 bf16 g-slots.
//   chunk = ((oT*64 + kt)*2 + ks)*64 + lane, o=oT*32+(lane&31), i=kt*4+ks*2+(lane>>5)

// Fused prep: blocks [0,256) pack W into fragment order; [256,512) do
// per-block min/max partials of x.
__global__ void __launch_bounds__(256) prep_kernel(const float* __restrict__ coef,
                                                   const float* __restrict__ scale,
                                                   const float* __restrict__ x,
                                                   unsigned short* __restrict__ wf,
                                                   float* __restrict__ part, int n4) {
  const int t = threadIdx.x;
  if (blockIdx.x < 256) {
    int idx = blockIdx.x * 256 + t;        // o*256 + i
    int o = idx >> 8, i = idx & 255;
    float s = scale[idx];
    const float* c = coef + (size_t)idx * 5;
    ushort8 v;
    v[0] = f2bf(c[0] * s); v[1] = f2bf(c[1] * s); v[2] = f2bf(c[2] * s);
    v[3] = f2bf(c[3] * s); v[4] = f2bf(c[4] * s);
    v[5] = 0; v[6] = 0; v[7] = 0;
    int chunk = (((o >> 5) * 64 + (i >> 2)) * 2 + ((i >> 1) & 1)) * 64
                + (i & 1) * 32 + (o & 31);
    *(ushort8*)(wf + (size_t)chunk * 8) = v;
  } else {
    int mb = blockIdx.x - 256;
    const float4* x4 = (const float4*)x;
    float lmin = 1e30f, lmax = -1e30f;
    for (int i = mb * 256 + t; i < n4; i += 256 * 256) {
      float4 v = x4[i];
      lmin = fminf(lmin, fminf(fminf(v.x, v.y), fminf(v.z, v.w)));
      lmax = fmaxf(lmax, fmaxf(fmaxf(v.x, v.y), fmaxf(v.z, v.w)));
    }
    #pragma unroll
    for (int off = 32; off >= 1; off >>= 1) {
      lmin = fminf(lmin, __shfl_down(lmin, off, 64));
      lmax = fmaxf(lmax, __shfl_down(lmax, off, 64));
    }
    __shared__ float smn[4], smx[4];
    if ((t & 63) == 0) { smn[t >> 6] = lmin; smx[t >> 6] = lmax; }
    __syncthreads();
    if (t == 0) {
      part[2 * mb]     = fminf(fminf(smn[0], smn[1]), fminf(smn[2], smn[3]));
      part[2 * mb + 1] = fmaxf(fmaxf(smx[0], smx[1]), fmaxf(smx[2], smx[3]));
    }
  }
}

// Lean basis octet: where(d<1,1-d^3,0) == max(1-d*d*|d|,0); eps dropped
// (sum >= 0.98 always); truncating bf16 pack via v_perm.
__device__ __forceinline__ bf16x8 basisfrag(float xval, float scA, float scB) {
  float xn = fmaf(xval, scA, scB);
  float d0 = xn + 1.0f, d1 = xn + 0.5f, d3 = xn - 0.5f, d4 = xn - 1.0f;
  float b0 = fmaxf(fmaf(d0 * d0, -fabsf(d0), 1.0f), 0.0f);
  float b1 = fmaxf(fmaf(d1 * d1, -fabsf(d1), 1.0f), 0.0f);
  float b2 = fmaxf(fmaf(xn * xn, -fabsf(xn), 1.0f), 0.0f);
  float b3 = fmaxf(fmaf(d3 * d3, -fabsf(d3), 1.0f), 0.0f);
  float b4 = fmaxf(fmaf(d4 * d4, -fabsf(d4), 1.0f), 0.0f);
  float sum = ((b0 + b1) + (b2 + b3)) + b4;
  float inv = __builtin_amdgcn_rcpf(sum);
  b0 *= inv; b1 *= inv; b2 *= inv; b3 *= inv; b4 *= inv;
  frag_u r;
  r.u.x = __builtin_amdgcn_perm(__float_as_uint(b1), __float_as_uint(b0), 0x07060302u);
  r.u.y = __builtin_amdgcn_perm(__float_as_uint(b3), __float_as_uint(b2), 0x07060302u);
  r.u.z = __float_as_uint(b4) >> 16;
  r.u.w = 0u;
  return r.v;
}

__global__ void __launch_bounds__(256, 4) kan_gemm(
    const float* __restrict__ x,            // [32768][256]
    const unsigned short* __restrict__ wf,  // fragment-ordered W, 1 MB
    const float* __restrict__ bias,         // [256]
    const float* __restrict__ part,         // 256 {min,max} partials
    float* __restrict__ out)                // [32768][256], pre-zeroed
{
  // B chunk buffers: chunk = 2 kt = 16 segs x 1 KB -> 2 x 16 KB
  __shared__ __align__(16) unsigned short Bb[2][8192];
  __shared__ float2 red[4];

  const int t = threadIdx.x;
  const int lane = t & 63;
  const int wm = t >> 6;                     // 4 waves stacked in m
  const int l31 = lane & 31, lh = lane >> 5;
  const int bRow = blockIdx.x * 128;
  const int bCol = blockIdx.y * 128;
  const int kb   = blockIdx.z;               // K half: kt_global = kb*32 + ktL
  const int row  = bRow + wm * 32 + l31;

  // ---- B chunk staging: 16 segs of 1 KB; each wave DMAs 4 (lane-linear) ----
  auto stage = [&](int c, int buf) {
    #pragma unroll
    for (int r = 0; r < 4; ++r) {
      int idx = r * 4 + wm;                  // wave-uniform; oTl=idx>>2, ktr=(idx>>1)&1, ks=idx&1
      int ktg = kb * 32 + c * 2 + ((idx >> 1) & 1);
      const unsigned short* src = wf +
          ((size_t)(((blockIdx.y * 4 + (idx >> 2)) * 64 + ktg) * 2 + (idx & 1))) * 512
          + (size_t)lane * 8;
      __builtin_amdgcn_global_load_lds(
          (const __attribute__((address_space(1))) unsigned int*)src,
          (__attribute__((address_space(3))) unsigned int*)(&Bb[buf][idx * 512 + lane * 8]),
          16, 0, 0);
    }
  };

  const float* xrow = x + (size_t)row * IN_SZ + kb * 128;

  // prologue: chunk 0 DMA + chunk-0 x loads in flight during minmax reduce
  stage(0, 0);
  float4 xq[2], xqn[2];
  xq[0] = *(const float4*)(xrow + 0);
  xq[1] = *(const float4*)(xrow + 4);

  float2 p = ((const float2*)part)[t];
  float mn = p.x, mx = p.y;
  #pragma unroll
  for (int off = 32; off >= 1; off >>= 1) {
    mn = fminf(mn, __shfl_down(mn, off, 64));
    mx = fmaxf(mx, __shfl_down(mx, off, 64));
  }
  if (lane == 0) red[wm] = make_float2(mn, mx);
  __syncthreads();
  mn = fminf(fminf(red[0].x, red[1].x), fminf(red[2].x, red[3].x));
  mx = fmaxf(fmaxf(red[0].y, red[1].y), fmaxf(red[2].y, red[3].y));
  const float scA = 2.0f / (mx - mn + EPSF);
  const float scB = -mn * scA - 1.0f;

  floatx16 acc[4] = {};

  // ---- K loop: 16 chunks x 2 kt; ONE barrier per chunk ----
  for (int c = 0; c < 16; ++c) {
    const int buf = c & 1;

    __syncthreads();   // vmcnt(0) drain == wait for chunk-c DMA (issued one
                       // chunk ago); also fences prev-buf LDS reads.

    if (c < 15) {      // next chunk's DMA + x loads in flight for a full chunk
      stage(c + 1, buf ^ 1);
      xqn[0] = *(const float4*)(xrow + (c + 1) * 8);
      xqn[1] = *(const float4*)(xrow + (c + 1) * 8 + 4);
    }

    #pragma unroll
    for (int ktr = 0; ktr < 2; ++ktr) {
      // A fragments from registers: i = kb*128 + (c*2+ktr)*4 + ks*2 + lh
      float xv0 = lh ? xq[ktr].y : xq[ktr].x;    // ks=0
      float xv1 = lh ? xq[ktr].w : xq[ktr].z;    // ks=1
      bf16x8 af0 = basisfrag(xv0, scA, scB);
      bf16x8 af1 = basisfrag(xv1, scA, scB);

      #pragma unroll
      for (int ni = 0; ni < 4; ++ni) {
        bf16x8 b0 = *(const bf16x8*)(&Bb[buf][((ni * 2 + ktr) * 2 + 0) * 512 + lane * 8]);
        acc[ni] = __builtin_amdgcn_mfma_f32_32x32x16_bf16(af0, b0, acc[ni], 0, 0, 0);
      }
      #pragma unroll
      for (int ni = 0; ni < 4; ++ni) {
        bf16x8 b1 = *(const bf16x8*)(&Bb[buf][((ni * 2 + ktr) * 2 + 1) * 512 + lane * 8]);
        acc[ni] = __builtin_amdgcn_mfma_f32_32x32x16_bf16(af1, b1, acc[ni], 0, 0, 0);
      }
    }

    xq[0] = xqn[0];
    xq[1] = xqn[1];
  }

  // epilogue: atomicAdd the K-half partial. C/D col=lane&31,
  // row=(reg&3)+8*(reg>>2)+4*(lane>>5) [m74/m101]. kb==0 adds bias.
  #pragma unroll
  for (int ni = 0; ni < 4; ++ni) {
    int o = bCol + ni * 32 + l31;
    float bs = (kb == 0) ? bias[o] : 0.0f;
    int rb = bRow + wm * 32 + 4 * lh;
    #pragma unroll
    for (int reg = 0; reg < 16; ++reg) {
      int r = rb + (reg & 3) + 8 * (reg >> 2);
      atomicAdd(&out[(size_t)r * OUT_SZ + o], acc[ni][reg] + bs);
    }
  }
}

extern "C" void kernel_launch(void* const* d_in, const int* in_sizes, int n_in,
                              void* d_out, int out_size, void* d_ws, size_t ws_size,
                              hipStream_t stream) {
  const float* x     = (const float*)d_in[0];
  // d_in[1] = grid: linspace(-1,1,5), hardcoded
  const float* coef  = (const float*)d_in[2];
  const float* scale = (const float*)d_in[3];
  const float* bias  = (const float*)d_in[4];
  float* out = (float*)d_out;

  // ws: [0..2048) minmax partials (256 float2), [4096..) Wf (1 MB)
  size_t need = 4096 + (size_t)OUT_SZ * IN_SZ * 8 * 2;
  if (ws_size < need) return;

  float* part = (float*)d_ws;
  unsigned short* wf = (unsigned short*)((char*)d_ws + 4096);

  // zero out for the split-K atomic accumulation (capture-legal, every call)
  hipMemsetAsync(d_out, 0, (size_t)B_SZ * OUT_SZ * sizeof(float), stream);
  prep_kernel<<<512, 256, 0, stream>>>(coef, scale, x, wf, part,
                                       (B_SZ * IN_SZ) / 4);
  dim3 g(B_SZ / 128, OUT_SZ / 128, 2);
  kan_gemm<<<g, 256, 0, stream>>>(x, wf, bias, part, out);
}